// Round 1
// baseline (748.392 us; speedup 1.0000x reference)
//
#include <hip/hip_runtime.h>

// TransD scoring kernel.
// out[b] = rp[rel[b]] * (hp·h − tp·t) + (h − t) + r[rel[b]]
// where h,hp,t,tp are 128-float entity-table gathers and r,rp relation gathers.
// Memory-bound: ~42 MB gather reads + 8.4 MB writes per call.

#define ENT_DIM 128

__global__ __launch_bounds__(256) void transd_kernel(
    const int* __restrict__ head,
    const int* __restrict__ relation,
    const int* __restrict__ tail,
    const float* __restrict__ ent_emb,
    const float* __restrict__ ent_map_emb,
    const float* __restrict__ rel_emb,
    const float* __restrict__ rel_map_emb,
    float* __restrict__ out,
    int batch)
{
    // One 32-lane half-wave per batch row; each lane owns a float4 (4 of 128 dims).
    int tid  = blockIdx.x * blockDim.x + threadIdx.x;
    int row  = tid >> 5;
    int lane = tid & 31;
    if (row >= batch) return;

    int hidx = head[row];
    int tidx = tail[row];
    int ridx = relation[row];

    const float4* h4  = (const float4*)(ent_emb     + (size_t)hidx * ENT_DIM);
    const float4* hp4 = (const float4*)(ent_map_emb + (size_t)hidx * ENT_DIM);
    const float4* t4  = (const float4*)(ent_emb     + (size_t)tidx * ENT_DIM);
    const float4* tp4 = (const float4*)(ent_map_emb + (size_t)tidx * ENT_DIM);
    const float4* r4  = (const float4*)(rel_emb     + (size_t)ridx * ENT_DIM);
    const float4* rp4 = (const float4*)(rel_map_emb + (size_t)ridx * ENT_DIM);

    float4 h  = h4[lane];
    float4 hp = hp4[lane];
    float4 t  = t4[lane];
    float4 tp = tp4[lane];

    // Partial of (hp·h − tp·t) over this lane's 4 dims.
    float part = hp.x * h.x + hp.y * h.y + hp.z * h.z + hp.w * h.w
               - (tp.x * t.x + tp.y * t.y + tp.z * t.z + tp.w * t.w);

    // Reduce across the 32-lane group: xor masks 16..1 never cross the
    // 32-lane boundary, so each half-wave reduces independently.
    #pragma unroll
    for (int m = 16; m > 0; m >>= 1)
        part += __shfl_xor(part, m, 64);

    float4 r  = r4[lane];
    float4 rp = rp4[lane];

    float4 o;
    o.x = rp.x * part + h.x - t.x + r.x;
    o.y = rp.y * part + h.y - t.y + r.y;
    o.z = rp.z * part + h.z - t.z + r.z;
    o.w = rp.w * part + h.w - t.w + r.w;

    ((float4*)(out + (size_t)row * ENT_DIM))[lane] = o;
}

extern "C" void kernel_launch(void* const* d_in, const int* in_sizes, int n_in,
                              void* d_out, int out_size, void* d_ws, size_t ws_size,
                              hipStream_t stream) {
    const int*   head        = (const int*)d_in[0];
    const int*   relation    = (const int*)d_in[1];
    const int*   tail        = (const int*)d_in[2];
    const float* ent_emb     = (const float*)d_in[3];
    const float* ent_map_emb = (const float*)d_in[4];
    const float* rel_emb     = (const float*)d_in[5];
    const float* rel_map_emb = (const float*)d_in[6];
    float* out = (float*)d_out;

    int batch = in_sizes[0];

    int threads = 256;                       // 8 rows per block (32 lanes/row)
    int total   = batch * 32;
    int blocks  = (total + threads - 1) / threads;

    transd_kernel<<<blocks, threads, 0, stream>>>(
        head, relation, tail, ent_emb, ent_map_emb, rel_emb, rel_map_emb,
        out, batch);
}